// Round 1
// baseline (33.948 us; speedup 1.0000x reference)
//
#include <hip/hip_runtime.h>

// Problem constants (fixed shapes from setup_inputs)
#define N_PTS 2048
#define D_DIM 64
#define N_J   20
#define KDIM  192   // 64 (P) + 120 (W features) + 8 pad
#define T_TILES 32  // N_PTS / 64
#define NTILES 528  // T*(T+1)/2 upper-triangle 64x64 tiles
#define NUM_PAIRS_D 2098175.0  // N*(N+1)/2 - 1 (reference normalizer)

// ---------------------------------------------------------------------------
// Kernel 1: build fused feature matrix G[N][192] and sq_norms[N].
//   G[i][0:64]    = predictions[i]
//   G[i][64:184]  = per-joint lifted features w (6 per joint):
//                   (x^2, y^2, z^2, sqrt2*xy, sqrt2*xz, sqrt2*yz) of unit u
//   G[i][184:192] = 0 (pad)
// so that  G_i[0:64]  . G_j[0:64]  = p_i . p_j
//          G_i[64:184]. G_j[64:184]= sum_k cos_k^2
// ---------------------------------------------------------------------------
__global__ __launch_bounds__(64)
void precompute_kernel(const float* __restrict__ pred,
                       const float* __restrict__ data,
                       float* __restrict__ G,
                       float* __restrict__ sq) {
    const int i = blockIdx.x;      // row 0..2047
    const int t = threadIdx.x;     // 0..63

    // P part + squared norm
    float p = pred[i * D_DIM + t];
    G[i * KDIM + t] = p;
    float v = p * p;
    #pragma unroll
    for (int off = 32; off > 0; off >>= 1) v += __shfl_down(v, off);
    if (t == 0) sq[i] = v;

    // W part (20 joints)
    if (t < N_J) {
        const float x0 = data[(i * N_J + t) * 3 + 0];
        const float y0 = data[(i * N_J + t) * 3 + 1];
        const float z0 = data[(i * N_J + t) * 3 + 2];
        const float n2 = x0 * x0 + y0 * y0 + z0 * z0;
        const float inv = rsqrtf(fmaxf(n2, 1e-30f));
        const float x = x0 * inv, y = y0 * inv, z = z0 * inv;
        const float s2 = 1.4142135623730951f;
        float* g = &G[i * KDIM + D_DIM + t * 6];
        g[0] = x * x;
        g[1] = y * y;
        g[2] = z * z;
        g[3] = s2 * x * y;
        g[4] = s2 * x * z;
        g[5] = s2 * y * z;
    }
    // zero padding cols 184..191
    if (t < 8) G[i * KDIM + D_DIM + N_J * 6 + t] = 0.0f;
}

// ---------------------------------------------------------------------------
// Kernel 2: pairwise tile kernel. One block per 64x64 upper-triangle tile.
// 256 threads, each computes a 4x4 micro-tile of pairs with two accumulators
// (acc1 = p-dot over k in [0,64), acc2 = w-dot over k in [64,192)).
// LDS tiles stored k-major (transposed) so fragment reads are float4.
// ---------------------------------------------------------------------------
__global__ __launch_bounds__(256)
void pairloss_kernel(const float* __restrict__ G,
                     const float* __restrict__ sq,
                     float* __restrict__ partials) {
    __shared__ float At[64][64];   // [k_local][row]
    __shared__ float Bt[64][64];   // [k_local][col]

    // decode triangular tile index -> (ib, jb), jb >= ib
    int t = blockIdx.x;
    int ib = 0;
    while (t >= T_TILES - ib) { t -= (T_TILES - ib); ++ib; }
    const int jb = ib + t;

    const int tid  = threadIdx.x;
    const int lrow = tid & 63;     // 0..63 : row within tile for staging
    const int kq   = tid >> 6;     // 0..3  : k-quarter for staging
    const int ty   = tid >> 4;     // 0..15 : micro-tile row group
    const int tx   = tid & 15;     // 0..15 : micro-tile col group

    float acc1[4][4] = {{0.f}};
    float acc2[4][4] = {{0.f}};

    const float* __restrict__ rowA = &G[(ib * 64 + lrow) * KDIM];
    const float* __restrict__ rowB = &G[(jb * 64 + lrow) * KDIM];

    #pragma unroll
    for (int kc = 0; kc < 3; ++kc) {
        __syncthreads();   // protect previous iteration's reads
        // stage 64 rows x 64 k, transposed into LDS
        #pragma unroll
        for (int q = 0; q < 4; ++q) {
            const int kl = kq * 16 + q * 4;
            const float4 a = *(const float4*)&rowA[kc * 64 + kl];
            At[kl + 0][lrow] = a.x;
            At[kl + 1][lrow] = a.y;
            At[kl + 2][lrow] = a.z;
            At[kl + 3][lrow] = a.w;
            const float4 b = *(const float4*)&rowB[kc * 64 + kl];
            Bt[kl + 0][lrow] = b.x;
            Bt[kl + 1][lrow] = b.y;
            Bt[kl + 2][lrow] = b.z;
            Bt[kl + 3][lrow] = b.w;
        }
        __syncthreads();

        if (kc == 0) {
            #pragma unroll 8
            for (int kk = 0; kk < 64; ++kk) {
                const float4 av = *(const float4*)&At[kk][ty * 4];
                const float4 bv = *(const float4*)&Bt[kk][tx * 4];
                const float ar[4] = {av.x, av.y, av.z, av.w};
                const float br[4] = {bv.x, bv.y, bv.z, bv.w};
                #pragma unroll
                for (int r = 0; r < 4; ++r)
                    #pragma unroll
                    for (int c = 0; c < 4; ++c)
                        acc1[r][c] = fmaf(ar[r], br[c], acc1[r][c]);
            }
        } else {
            #pragma unroll 8
            for (int kk = 0; kk < 64; ++kk) {
                const float4 av = *(const float4*)&At[kk][ty * 4];
                const float4 bv = *(const float4*)&Bt[kk][tx * 4];
                const float ar[4] = {av.x, av.y, av.z, av.w};
                const float br[4] = {bv.x, bv.y, bv.z, bv.w};
                #pragma unroll
                for (int r = 0; r < 4; ++r)
                    #pragma unroll
                    for (int c = 0; c < 4; ++c)
                        acc2[r][c] = fmaf(ar[r], br[c], acc2[r][c]);
            }
        }
    }

    // epilogue: per-pair |dist - dis|, strict upper triangle only
    const int i0 = ib * 64 + ty * 4;
    const int j0 = jb * 64 + tx * 4;
    float sqi[4], sqj[4];
    #pragma unroll
    for (int r = 0; r < 4; ++r) sqi[r] = sq[i0 + r];
    #pragma unroll
    for (int c = 0; c < 4; ++c) sqj[c] = sq[j0 + c];

    float local = 0.0f;
    #pragma unroll
    for (int r = 0; r < 4; ++r) {
        #pragma unroll
        for (int c = 0; c < 4; ++c) {
            const int i = i0 + r;
            const int j = j0 + c;
            if (j > i) {
                const float d2   = fmaxf(sqi[r] + sqj[c] - 2.0f * acc1[r][c], 0.0f);
                const float dist = sqrtf(d2);
                const float s    = fmaxf((float)N_J - acc2[r][c], 0.0f);
                const float dis  = sqrtf(s);
                local += fabsf(dist - dis);
            }
        }
    }

    // block reduction -> one partial per block (deterministic)
    #pragma unroll
    for (int off = 32; off > 0; off >>= 1) local += __shfl_down(local, off);
    __shared__ float wsum[4];
    if ((tid & 63) == 0) wsum[tid >> 6] = local;
    __syncthreads();
    if (tid == 0) partials[blockIdx.x] = wsum[0] + wsum[1] + wsum[2] + wsum[3];
}

// ---------------------------------------------------------------------------
// Kernel 3: final deterministic reduction in f64, divide by pair count.
// ---------------------------------------------------------------------------
__global__ __launch_bounds__(256)
void finalize_kernel(const float* __restrict__ partials, float* __restrict__ out) {
    __shared__ double sh[256];
    double s = 0.0;
    for (int i = threadIdx.x; i < NTILES; i += 256) s += (double)partials[i];
    sh[threadIdx.x] = s;
    __syncthreads();
    for (int off = 128; off > 0; off >>= 1) {
        if (threadIdx.x < off) sh[threadIdx.x] += sh[threadIdx.x + off];
        __syncthreads();
    }
    if (threadIdx.x == 0) out[0] = (float)(sh[0] / NUM_PAIRS_D);
}

// ---------------------------------------------------------------------------
extern "C" void kernel_launch(void* const* d_in, const int* in_sizes, int n_in,
                              void* d_out, int out_size, void* d_ws, size_t ws_size,
                              hipStream_t stream) {
    const float* pred = (const float*)d_in[0];   // [2048, 64] f32
    const float* data = (const float*)d_in[1];   // [2048, 20, 3] f32
    float* out = (float*)d_out;                  // scalar f32

    // workspace layout
    char* ws = (char*)d_ws;
    float* G        = (float*)(ws);                                 // 2048*192*4 = 1572864 B
    float* sq       = (float*)(ws + (size_t)N_PTS * KDIM * 4);      // 2048*4    = 8192 B
    float* partials = (float*)(ws + (size_t)N_PTS * KDIM * 4 + (size_t)N_PTS * 4); // 528*4 B

    precompute_kernel<<<N_PTS, 64, 0, stream>>>(pred, data, G, sq);
    pairloss_kernel<<<NTILES, 256, 0, stream>>>(G, sq, partials);
    finalize_kernel<<<1, 256, 0, stream>>>(partials, out);
}